// Round 1
// baseline (4420.499 us; speedup 1.0000x reference)
//
#include <hip/hip_runtime.h>
#include <hip/hip_bf16.h>
#include <math.h>

// Problem constants
#define Bn 4
#define Tn 4096
#define Dn 1024
#define Kn 128
#define TWOK 256
#define Hn 8
#define KHn 16
#define Mmlp 4096
#define NROW (Bn * Tn)          // 16384
#define TAPS 32

__device__ __forceinline__ float sigmoidf_(float x) { return 1.f / (1.f + expf(-x)); }

// ---------------------------------------------------------------------------
// LayerNorm: out[row] = (x - mean)/sqrt(var+1e-5) * g + b   (D=1024, 256 thr)
// ---------------------------------------------------------------------------
__global__ __launch_bounds__(256) void ln_kernel(const float* __restrict__ x,
                                                 const float* __restrict__ g,
                                                 const float* __restrict__ b,
                                                 float* __restrict__ out) {
    const int row = blockIdx.x;
    const float4* xr = (const float4*)(x + (size_t)row * Dn);
    float4 v = xr[threadIdx.x];
    float s = v.x + v.y + v.z + v.w;
    float ss = v.x * v.x + v.y * v.y + v.z * v.z + v.w * v.w;
    for (int off = 32; off; off >>= 1) {
        s += __shfl_down(s, off);
        ss += __shfl_down(ss, off);
    }
    __shared__ float rs[4], rss[4];
    const int wv = threadIdx.x >> 6, ln = threadIdx.x & 63;
    if (ln == 0) { rs[wv] = s; rss[wv] = ss; }
    __syncthreads();
    s = rs[0] + rs[1] + rs[2] + rs[3];
    ss = rss[0] + rss[1] + rss[2] + rss[3];
    const float mean = s * (1.f / Dn);
    const float var = ss * (1.f / Dn) - mean * mean;
    const float inv = rsqrtf(var + 1e-5f);
    const float4 gg = ((const float4*)g)[threadIdx.x];
    const float4 bb = ((const float4*)b)[threadIdx.x];
    float4 o;
    o.x = (v.x - mean) * inv * gg.x + bb.x;
    o.y = (v.y - mean) * inv * gg.y + bb.y;
    o.z = (v.z - mean) * inv * gg.z + bb.z;
    o.w = (v.w - mean) * inv * gg.w + bb.w;
    ((float4*)(out + (size_t)row * Dn))[threadIdx.x] = o;
}

// ---------------------------------------------------------------------------
// GEMM: C[M,N] = A[M,K] @ B[N,K]^T  (both row-major, reduction over K)
// 128x128 tile, BK=16, 256 threads, 8x8 microtile (split 4+4 at stride 64).
// Epilogues: 0 none | 1 C=sigmoid(*bias)*acc | 2 C=aux1+sig(acc+bias[c])*aux2
//            3 C=silu(acc+bias[c]) | 4 C=acc+bias[c]+aux1
// ---------------------------------------------------------------------------
template <int EPI>
__global__ __launch_bounds__(256) void gemm_tn(const float* __restrict__ A,
                                               const float* __restrict__ B,
                                               float* __restrict__ C,
                                               int M, int N, int Kd,
                                               const float* __restrict__ bias,
                                               const float* __restrict__ aux1,
                                               const float* __restrict__ aux2) {
    __shared__ float As[16][132];
    __shared__ float Bs[16][132];
    const int tid = threadIdx.x;
    const int tx = tid & 15, ty = tid >> 4;
    const int m0 = blockIdx.y * 128, n0 = blockIdx.x * 128;

    float acc[8][8];
#pragma unroll
    for (int i = 0; i < 8; ++i)
#pragma unroll
        for (int j = 0; j < 8; ++j) acc[i][j] = 0.f;

    const float* Ap = A + (size_t)m0 * Kd;
    const float* Bp = B + (size_t)n0 * Kd;

    for (int k0 = 0; k0 < Kd; k0 += 16) {
        float4 ar[2], br[2];
#pragma unroll
        for (int q = 0; q < 2; ++q) {
            const int idx = q * 256 + tid;
            const int row = idx >> 2, kg = (idx & 3) << 2;
            ar[q] = *(const float4*)(Ap + (size_t)row * Kd + k0 + kg);
            br[q] = *(const float4*)(Bp + (size_t)row * Kd + k0 + kg);
        }
        __syncthreads();
#pragma unroll
        for (int q = 0; q < 2; ++q) {
            const int idx = q * 256 + tid;
            const int row = idx >> 2, kg = (idx & 3) << 2;
            As[kg + 0][row] = ar[q].x; As[kg + 1][row] = ar[q].y;
            As[kg + 2][row] = ar[q].z; As[kg + 3][row] = ar[q].w;
            Bs[kg + 0][row] = br[q].x; Bs[kg + 1][row] = br[q].y;
            Bs[kg + 2][row] = br[q].z; Bs[kg + 3][row] = br[q].w;
        }
        __syncthreads();
#pragma unroll
        for (int kk = 0; kk < 16; ++kk) {
            const float4 a0 = *(const float4*)&As[kk][4 * ty];
            const float4 a1 = *(const float4*)&As[kk][64 + 4 * ty];
            const float4 b0 = *(const float4*)&Bs[kk][4 * tx];
            const float4 b1 = *(const float4*)&Bs[kk][64 + 4 * tx];
            const float av[8] = {a0.x, a0.y, a0.z, a0.w, a1.x, a1.y, a1.z, a1.w};
            const float bv[8] = {b0.x, b0.y, b0.z, b0.w, b1.x, b1.y, b1.z, b1.w};
#pragma unroll
            for (int i = 0; i < 8; ++i)
#pragma unroll
                for (int j = 0; j < 8; ++j) acc[i][j] += av[i] * bv[j];
        }
    }

    float s_pre = 0.f;
    if constexpr (EPI == 1) s_pre = sigmoidf_(bias[0]);

#pragma unroll
    for (int rg = 0; rg < 2; ++rg)
#pragma unroll
        for (int i = 0; i < 4; ++i) {
            const int r = m0 + 64 * rg + 4 * ty + i;
            const size_t ro = (size_t)r * N;
#pragma unroll
            for (int cg = 0; cg < 2; ++cg) {
                const int c = n0 + 64 * cg + 4 * tx;
                float o[4];
#pragma unroll
                for (int j = 0; j < 4; ++j) {
                    const float a = acc[rg * 4 + i][cg * 4 + j];
                    if constexpr (EPI == 0) {
                        o[j] = a;
                    } else if constexpr (EPI == 1) {
                        o[j] = s_pre * a;
                    } else if constexpr (EPI == 2) {
                        o[j] = aux1[ro + c + j] + sigmoidf_(a + bias[c + j]) * aux2[ro + c + j];
                    } else if constexpr (EPI == 3) {
                        const float t = a + bias[c + j];
                        o[j] = t * sigmoidf_(t);
                    } else {
                        o[j] = a + bias[c + j] + aux1[ro + c + j];
                    }
                }
                float4 v4 = {o[0], o[1], o[2], o[3]};
                *(float4*)(C + ro + c) = v4;
            }
        }
}

// ---------------------------------------------------------------------------
// Depthwise causal conv (ker=4) + bias + SiLU + memory injection, then
// transpose-write into [B, K, T] split real/imag planes.
// beta, mgp: [B, T, 2K].  Block: 32 t x 32 c tile, 256 threads.
// ---------------------------------------------------------------------------
__global__ __launch_bounds__(256) void conv_mem_kernel(const float* __restrict__ beta,
                                                       const float* __restrict__ mgp,
                                                       const float* __restrict__ conv_w,
                                                       const float* __restrict__ conv_b,
                                                       float* __restrict__ ur,
                                                       float* __restrict__ ui) {
    const int b = blockIdx.z;
    const int t0 = blockIdx.y * 32;
    const int c0 = blockIdx.x * 32;
    const int tid = threadIdx.x;
    __shared__ float sb[35][33];
    __shared__ float sm[32][33];

    for (int idx = tid; idx < 35 * 32; idx += 256) {
        const int r = idx >> 5, c = idx & 31;
        const int t = t0 - 3 + r;
        sb[r][c] = (t >= 0) ? beta[((size_t)b * Tn + t) * TWOK + c0 + c] : 0.f;
    }
    for (int idx = tid; idx < 32 * 32; idx += 256) {
        const int r = idx >> 5, c = idx & 31;
        sm[r][c] = mgp[((size_t)b * Tn + t0 + r) * TWOK + c0 + c];
    }
    __syncthreads();

    const int cl = tid & 31;
    const int cglob = c0 + cl;
    const float w0 = conv_w[cglob * 4 + 0], w1 = conv_w[cglob * 4 + 1];
    const float w2 = conv_w[cglob * 4 + 2], w3 = conv_w[cglob * 4 + 3];
    const float cb = conv_b[cglob];
    const int tb = tid >> 5;
#pragma unroll
    for (int q = 0; q < 4; ++q) {
        const int tl = tb + 8 * q;
        float v = sb[tl + 0][cl] * w0 + sb[tl + 1][cl] * w1 +
                  sb[tl + 2][cl] * w2 + sb[tl + 3][cl] * w3 + cb;
        v = v * sigmoidf_(v);          // SiLU
        v += sm[tl][cl];               // + mg * (prev_eig @ memW^T)
        sm[tl][cl] = v;                // reuse sm as output tile
    }
    __syncthreads();

    for (int idx = tid; idx < 1024; idx += 256) {
        const int cc = idx >> 5, tl = idx & 31;
        const float v = sm[tl][cc];
        const int cg = c0 + cc;
        const size_t off = ((size_t)b * Kn + (cg & (Kn - 1))) * Tn + t0 + tl;
        if (cg < Kn) ur[off] = v; else ui[off] = v;
    }
}

// ---------------------------------------------------------------------------
// 32-tap complex FIR: c[t] = sum_d lam^d * u[t-d],  lam = mag * e^{i f}
// u layout [B, K, T]; block = (b, k, 256-t chunk)
// ---------------------------------------------------------------------------
__global__ __launch_bounds__(256) void fir_kernel(const float* __restrict__ ur,
                                                  const float* __restrict__ ui,
                                                  const float* __restrict__ log_decay,
                                                  const float* __restrict__ freq,
                                                  float* __restrict__ cr,
                                                  float* __restrict__ ci) {
    const int b = blockIdx.z, k = blockIdx.y, t0 = blockIdx.x * 256;
    const int tid = threadIdx.x;
    __shared__ float sur[288], sui[288], slr[TAPS], sli[TAPS];
    const float* urp = ur + ((size_t)b * Kn + k) * Tn;
    const float* uip = ui + ((size_t)b * Kn + k) * Tn;
    for (int i = tid; i < 287; i += 256) {
        const int t = t0 - 31 + i;
        sur[i] = (t >= 0) ? urp[t] : 0.f;
        sui[i] = (t >= 0) ? uip[t] : 0.f;
    }
    if (tid == 0) {
        const float mag = sigmoidf_(log_decay[k]);
        const float f = freq[k];
        const float lr = mag * cosf(f), li = mag * sinf(f);
        float pr = 1.f, pi = 0.f;
        for (int d = 0; d < TAPS; ++d) {
            slr[d] = pr; sli[d] = pi;
            const float nr = pr * lr - pi * li;
            const float ni = pr * li + pi * lr;
            pr = nr; pi = ni;
        }
    }
    __syncthreads();
    float accr = 0.f, acci = 0.f;
#pragma unroll
    for (int d = 0; d < TAPS; ++d) {
        const float vr = sur[tid + 31 - d];
        const float vi = sui[tid + 31 - d];
        accr += slr[d] * vr - sli[d] * vi;
        acci += slr[d] * vi + sli[d] * vr;
    }
    const size_t off = ((size_t)b * Kn + k) * Tn + t0 + tid;
    cr[off] = accr;
    ci[off] = acci;
}

// ---------------------------------------------------------------------------
// Per-head coupling: eig[b,t,h*16+j]     = sum_k coup[h,j,k]*cr[b,h*16+k,t]
//                    eig[b,t,128+h*16+j] = sum_k coup[h,j,k]*ci[b,h*16+k,t]
// ---------------------------------------------------------------------------
__global__ __launch_bounds__(256) void coupling_kernel(const float* __restrict__ cr,
                                                       const float* __restrict__ ci,
                                                       const float* __restrict__ coup,
                                                       float* __restrict__ eig) {
    const int b = blockIdx.z, h = blockIdx.y, t0 = blockIdx.x * 256;
    const int tid = threadIdx.x;
    __shared__ float sc[16][16];
    sc[tid >> 4][tid & 15] = coup[h * 256 + tid];
    __syncthreads();
    const int t = t0 + tid;
    float orr[16], oii[16];
#pragma unroll
    for (int j = 0; j < 16; ++j) { orr[j] = 0.f; oii[j] = 0.f; }
    for (int k2 = 0; k2 < 16; ++k2) {
        const float vr = cr[((size_t)b * Kn + h * 16 + k2) * Tn + t];
        const float vi = ci[((size_t)b * Kn + h * 16 + k2) * Tn + t];
#pragma unroll
        for (int j = 0; j < 16; ++j) {
            orr[j] += sc[j][k2] * vr;
            oii[j] += sc[j][k2] * vi;
        }
    }
    const size_t base = ((size_t)b * Tn + t) * TWOK + h * 16;
#pragma unroll
    for (int j = 0; j < 16; ++j) {
        eig[base + j] = orr[j];
        eig[base + Kn + j] = oii[j];
    }
}

// ---------------------------------------------------------------------------
extern "C" void kernel_launch(void* const* d_in, const int* in_sizes, int n_in,
                              void* d_out, int out_size, void* d_ws, size_t ws_size,
                              hipStream_t stream) {
    const float* x          = (const float*)d_in[0];
    const float* prev_eig   = (const float*)d_in[1];
    const float* in_proj_w  = (const float*)d_in[2];
    const float* conv_w     = (const float*)d_in[3];
    const float* conv_b     = (const float*)d_in[4];
    const float* mem_gate   = (const float*)d_in[5];
    const float* mem_proj_w = (const float*)d_in[6];
    const float* log_decay  = (const float*)d_in[7];
    const float* frequency  = (const float*)d_in[8];
    const float* coupling   = (const float*)d_in[9];
    const float* out_proj_w = (const float*)d_in[10];
    const float* gate_w     = (const float*)d_in[11];
    const float* gate_b     = (const float*)d_in[12];
    const float* mlp_w1     = (const float*)d_in[13];
    const float* mlp_b1     = (const float*)d_in[14];
    const float* mlp_w2     = (const float*)d_in[15];
    const float* mlp_b2     = (const float*)d_in[16];
    const float* n1_g       = (const float*)d_in[17];
    const float* n1_b       = (const float*)d_in[18];
    const float* n2_g       = (const float*)d_in[19];
    const float* n2_b       = (const float*)d_in[20];

    float* out = (float*)d_out;          // x2: 16,777,216 floats
    float* eig = out + (size_t)NROW * Dn;  // eig output: 4,194,304 floats

    // Workspace layout (floats). Total = 67,108,864 floats = 256 MiB.
    float* w = (float*)d_ws;
    float* xn   = w;                        // [16384,1024]  live steps 1-8
    float* x1   = w + 16777216;             // [16384,1024]  live 8-end
    float* beta = w + 33554432;             // [16384,256]   live 2-4
    float* mgp  = w + 37748736;             // [16384,256]   live 3-4
    float* ur   = w + 41943040;             // [B,K,T]       live 4-5
    float* ui   = w + 44040192;
    float* crb  = w + 46137344;             // live 5-6
    float* cib  = w + 48234496;
    float* h1   = w + 33554432;             // [4096,4096]   live in mlp chunks (aliases beta..ci)
    float* o    = w + 50331648;             // [16384,1024]  live 7-8
    float* y    = w;                        // aliases xn    live 9-10

    // 1) xn = LN1(x)
    ln_kernel<<<dim3(NROW), dim3(256), 0, stream>>>(x, n1_g, n1_b, xn);
    // 2) beta = xn @ in_proj_w^T   [16384,256]
    gemm_tn<0><<<dim3(2, 128), dim3(256), 0, stream>>>(xn, in_proj_w, beta,
                                                       NROW, TWOK, Dn, nullptr, nullptr, nullptr);
    // 3) mgp = sigmoid(mem_gate) * (prev_eig @ mem_proj_w^T)
    gemm_tn<1><<<dim3(2, 128), dim3(256), 0, stream>>>(prev_eig, mem_proj_w, mgp,
                                                       NROW, TWOK, TWOK, mem_gate, nullptr, nullptr);
    // 4) conv + SiLU + mem inject, transpose to [B,K,T] real/imag
    conv_mem_kernel<<<dim3(8, 128, 4), dim3(256), 0, stream>>>(beta, mgp, conv_w, conv_b, ur, ui);
    // 5) complex FIR (exact eigenstate evolution, 32 taps)
    fir_kernel<<<dim3(16, 128, 4), dim3(256), 0, stream>>>(ur, ui, log_decay, frequency, crb, cib);
    // 6) per-head coupling -> eig (output #2)
    coupling_kernel<<<dim3(16, 8, 4), dim3(256), 0, stream>>>(crb, cib, coupling, eig);
    // 7) o = eig @ out_proj_w^T   [16384,1024]
    gemm_tn<0><<<dim3(8, 128), dim3(256), 0, stream>>>(eig, out_proj_w, o,
                                                       NROW, Dn, TWOK, nullptr, nullptr, nullptr);
    // 8) x1 = x + sigmoid(xn @ gate_w^T + gate_b) * o
    gemm_tn<2><<<dim3(8, 128), dim3(256), 0, stream>>>(xn, gate_w, x1,
                                                       NROW, Dn, Dn, gate_b, x, o);
    // 9) y = LN2(x1)   (y aliases xn, which is now dead)
    ln_kernel<<<dim3(NROW), dim3(256), 0, stream>>>(x1, n2_g, n2_b, y);
    // 10) MLP in 4 row-chunks of 4096: x2 = x1 + silu(y@w1^T+b1)@w2^T + b2
    for (int ck = 0; ck < 4; ++ck) {
        const size_t roff = (size_t)ck * 4096 * Dn;
        gemm_tn<3><<<dim3(32, 32), dim3(256), 0, stream>>>(y + roff, mlp_w1, h1,
                                                           4096, Mmlp, Dn, mlp_b1, nullptr, nullptr);
        gemm_tn<4><<<dim3(8, 32), dim3(256), 0, stream>>>(h1, mlp_w2, out + roff,
                                                          4096, Dn, Mmlp, mlp_b2, x1 + roff, nullptr);
    }
}

// Round 2
// 919.079 us; speedup vs baseline: 4.8097x; 4.8097x over previous
//
#include <hip/hip_runtime.h>
#include <hip/hip_bf16.h>
#include <math.h>

// Problem constants
#define Bn 4
#define Tn 4096
#define Dn 1024
#define Kn 128
#define TWOK 256
#define Hn 8
#define Mmlp 4096
#define NROW (Bn * Tn)          // 16384
#define TAPS 32

typedef __attribute__((ext_vector_type(8))) short bf16x8;   // 8 bf16 = 4 VGPRs
typedef __attribute__((ext_vector_type(4))) float floatx4;  // MFMA accumulator

__device__ __forceinline__ float sigmoidf_(float x) { return 1.f / (1.f + expf(-x)); }

// ---------------------------------------------------------------------------
// fp32 -> bf16 cast (weights / prev_eig), 4 elems/thread
// ---------------------------------------------------------------------------
__global__ __launch_bounds__(256) void f2bf_kernel(const float* __restrict__ in,
                                                   __hip_bfloat16* __restrict__ out,
                                                   int n) {
    const int i = (blockIdx.x * 256 + threadIdx.x) * 4;
    if (i >= n) return;
    const float4 v = *(const float4*)(in + i);
    out[i + 0] = __float2bfloat16(v.x);
    out[i + 1] = __float2bfloat16(v.y);
    out[i + 2] = __float2bfloat16(v.z);
    out[i + 3] = __float2bfloat16(v.w);
}

// ---------------------------------------------------------------------------
// LayerNorm (D=1024, 256 thr) -> bf16 output (only GEMMs consume LN output)
// ---------------------------------------------------------------------------
__global__ __launch_bounds__(256) void ln_kernel(const float* __restrict__ x,
                                                 const float* __restrict__ g,
                                                 const float* __restrict__ b,
                                                 __hip_bfloat16* __restrict__ out) {
    const int row = blockIdx.x;
    const float4* xr = (const float4*)(x + (size_t)row * Dn);
    float4 v = xr[threadIdx.x];
    float s = v.x + v.y + v.z + v.w;
    float ss = v.x * v.x + v.y * v.y + v.z * v.z + v.w * v.w;
    for (int off = 32; off; off >>= 1) {
        s += __shfl_down(s, off);
        ss += __shfl_down(ss, off);
    }
    __shared__ float rs[4], rss[4];
    const int wv = threadIdx.x >> 6, ln = threadIdx.x & 63;
    if (ln == 0) { rs[wv] = s; rss[wv] = ss; }
    __syncthreads();
    s = rs[0] + rs[1] + rs[2] + rs[3];
    ss = rss[0] + rss[1] + rss[2] + rss[3];
    const float mean = s * (1.f / Dn);
    const float var = ss * (1.f / Dn) - mean * mean;
    const float inv = rsqrtf(var + 1e-5f);
    const float4 gg = ((const float4*)g)[threadIdx.x];
    const float4 bb = ((const float4*)b)[threadIdx.x];
    __hip_bfloat16* op = out + (size_t)row * Dn + threadIdx.x * 4;
    op[0] = __float2bfloat16((v.x - mean) * inv * gg.x + bb.x);
    op[1] = __float2bfloat16((v.y - mean) * inv * gg.y + bb.y);
    op[2] = __float2bfloat16((v.z - mean) * inv * gg.z + bb.z);
    op[3] = __float2bfloat16((v.w - mean) * inv * gg.w + bb.w);
}

// ---------------------------------------------------------------------------
// bf16 MFMA GEMM (m97 structure): C[M,N] = A[M,K] @ B[N,K]^T
// A,B bf16 row-major (K contiguous). 128x128 tile, BK=32, 256 thr (4 waves),
// wave = 64x64 via 4x4 grid of 16x16x32 MFMA. global_load_lds width=16.
// Epilogues: 0 none | 1 C=sigmoid(bias[0])*acc | 2 C=aux1+sig(acc+bias[c])*aux2
//            3 C=silu(acc+bias[c]) | 4 C=acc+bias[c]+aux1
// ---------------------------------------------------------------------------
template <int EPI, typename CT>
__global__ __launch_bounds__(256) void gemm_bf(const ushort* __restrict__ A,
                                               const ushort* __restrict__ B,
                                               CT* __restrict__ C,
                                               int M, int N, int Kd,
                                               const float* __restrict__ bias,
                                               const float* __restrict__ aux1,
                                               const __hip_bfloat16* __restrict__ aux2) {
    __shared__ ushort As[128 * 32];   // contiguous: required by global_load_lds
    __shared__ ushort Bs[128 * 32];
    const int tid = threadIdx.x;
    const int m0 = blockIdx.y * 128, n0 = blockIdx.x * 128;
    const int wave = tid >> 6, lane = tid & 63;
    const int wm = wave >> 1, wn = wave & 1;
    const int mlane = lane & 15, quad = lane >> 4;

    floatx4 acc[4][4] = {};

    const ushort* Ap = A + (size_t)m0 * Kd;
    const ushort* Bp = B + (size_t)n0 * Kd;

    for (int k0 = 0; k0 < Kd; k0 += 32) {
#pragma unroll
        for (int q = 0; q < 2; ++q) {
            const int c = q * 256 + tid;          // chunk: 16B, row=c>>2, kcol=(c&3)*8
            const int row = c >> 2, kc = (c & 3) * 8;
            __builtin_amdgcn_global_load_lds(
                (const __attribute__((address_space(1))) void*)(Ap + (size_t)row * Kd + k0 + kc),
                (__attribute__((address_space(3))) void*)(As + c * 8), 16, 0, 0);
            __builtin_amdgcn_global_load_lds(
                (const __attribute__((address_space(1))) void*)(Bp + (size_t)row * Kd + k0 + kc),
                (__attribute__((address_space(3))) void*)(Bs + c * 8), 16, 0, 0);
        }
        __syncthreads();

        bf16x8 af[4], bfr[4];
#pragma unroll
        for (int t = 0; t < 4; ++t) {
            af[t]  = *(const bf16x8*)&As[(wm * 64 + t * 16 + mlane) * 32 + quad * 8];
            bfr[t] = *(const bf16x8*)&Bs[(wn * 64 + t * 16 + mlane) * 32 + quad * 8];
        }
#pragma unroll
        for (int i = 0; i < 4; ++i)
#pragma unroll
            for (int j = 0; j < 4; ++j)
                acc[i][j] = __builtin_amdgcn_mfma_f32_16x16x32_bf16(af[i], bfr[j], acc[i][j], 0, 0, 0);
        __syncthreads();
    }

    float s_pre = 0.f;
    if constexpr (EPI == 1) s_pre = sigmoidf_(bias[0]);

    const int cbase = n0 + wn * 64 + mlane;
#pragma unroll
    for (int i = 0; i < 4; ++i) {           // m-tile
#pragma unroll
        for (int r = 0; r < 4; ++r) {       // reg within acc
            const int row = m0 + wm * 64 + i * 16 + quad * 4 + r;
            const size_t ro = (size_t)row * N;
#pragma unroll
            for (int j = 0; j < 4; ++j) {   // n-tile
                const int col = cbase + j * 16;
                const float a = acc[i][j][r];
                float o;
                if constexpr (EPI == 0) {
                    o = a;
                } else if constexpr (EPI == 1) {
                    o = s_pre * a;
                } else if constexpr (EPI == 2) {
                    o = aux1[ro + col] + sigmoidf_(a + bias[col]) * __bfloat162float(aux2[ro + col]);
                } else if constexpr (EPI == 3) {
                    const float t = a + bias[col];
                    o = t * sigmoidf_(t);
                } else {
                    o = a + bias[col] + aux1[ro + col];
                }
                if constexpr (__is_same(CT, float)) C[ro + col] = o;
                else                                C[ro + col] = __float2bfloat16(o);
            }
        }
    }
}

// ---------------------------------------------------------------------------
// Depthwise causal conv (ker=4) + bias + SiLU + memory injection, then
// transpose-write into [B, K, T] split real/imag planes.
// ---------------------------------------------------------------------------
__global__ __launch_bounds__(256) void conv_mem_kernel(const float* __restrict__ beta,
                                                       const float* __restrict__ mgp,
                                                       const float* __restrict__ conv_w,
                                                       const float* __restrict__ conv_b,
                                                       float* __restrict__ ur,
                                                       float* __restrict__ ui) {
    const int b = blockIdx.z;
    const int t0 = blockIdx.y * 32;
    const int c0 = blockIdx.x * 32;
    const int tid = threadIdx.x;
    __shared__ float sb[35][33];
    __shared__ float sm[32][33];

    for (int idx = tid; idx < 35 * 32; idx += 256) {
        const int r = idx >> 5, c = idx & 31;
        const int t = t0 - 3 + r;
        sb[r][c] = (t >= 0) ? beta[((size_t)b * Tn + t) * TWOK + c0 + c] : 0.f;
    }
    for (int idx = tid; idx < 32 * 32; idx += 256) {
        const int r = idx >> 5, c = idx & 31;
        sm[r][c] = mgp[((size_t)b * Tn + t0 + r) * TWOK + c0 + c];
    }
    __syncthreads();

    const int cl = tid & 31;
    const int cglob = c0 + cl;
    const float w0 = conv_w[cglob * 4 + 0], w1 = conv_w[cglob * 4 + 1];
    const float w2 = conv_w[cglob * 4 + 2], w3 = conv_w[cglob * 4 + 3];
    const float cb = conv_b[cglob];
    const int tb = tid >> 5;
#pragma unroll
    for (int q = 0; q < 4; ++q) {
        const int tl = tb + 8 * q;
        float v = sb[tl + 0][cl] * w0 + sb[tl + 1][cl] * w1 +
                  sb[tl + 2][cl] * w2 + sb[tl + 3][cl] * w3 + cb;
        v = v * sigmoidf_(v);
        v += sm[tl][cl];
        sm[tl][cl] = v;
    }
    __syncthreads();

    for (int idx = tid; idx < 1024; idx += 256) {
        const int cc = idx >> 5, tl = idx & 31;
        const float v = sm[tl][cc];
        const int cg = c0 + cc;
        const size_t off = ((size_t)b * Kn + (cg & (Kn - 1))) * Tn + t0 + tl;
        if (cg < Kn) ur[off] = v; else ui[off] = v;
    }
}

// ---------------------------------------------------------------------------
// 32-tap complex FIR: c[t] = sum_d lam^d u[t-d]; |lam|<=0.232 => tap 32 ~ 1e-20
// ---------------------------------------------------------------------------
__global__ __launch_bounds__(256) void fir_kernel(const float* __restrict__ ur,
                                                  const float* __restrict__ ui,
                                                  const float* __restrict__ log_decay,
                                                  const float* __restrict__ freq,
                                                  float* __restrict__ cr,
                                                  float* __restrict__ ci) {
    const int b = blockIdx.z, k = blockIdx.y, t0 = blockIdx.x * 256;
    const int tid = threadIdx.x;
    __shared__ float sur[288], sui[288], slr[TAPS], sli[TAPS];
    const float* urp = ur + ((size_t)b * Kn + k) * Tn;
    const float* uip = ui + ((size_t)b * Kn + k) * Tn;
    for (int i = tid; i < 287; i += 256) {
        const int t = t0 - 31 + i;
        sur[i] = (t >= 0) ? urp[t] : 0.f;
        sui[i] = (t >= 0) ? uip[t] : 0.f;
    }
    if (tid == 0) {
        const float mag = sigmoidf_(log_decay[k]);
        const float f = freq[k];
        const float lr = mag * cosf(f), li = mag * sinf(f);
        float pr = 1.f, pi = 0.f;
        for (int d = 0; d < TAPS; ++d) {
            slr[d] = pr; sli[d] = pi;
            const float nr = pr * lr - pi * li;
            const float ni = pr * li + pi * lr;
            pr = nr; pi = ni;
        }
    }
    __syncthreads();
    float accr = 0.f, acci = 0.f;
#pragma unroll
    for (int d = 0; d < TAPS; ++d) {
        const float vr = sur[tid + 31 - d];
        const float vi = sui[tid + 31 - d];
        accr += slr[d] * vr - sli[d] * vi;
        acci += slr[d] * vi + sli[d] * vr;
    }
    const size_t off = ((size_t)b * Kn + k) * Tn + t0 + tid;
    cr[off] = accr;
    ci[off] = acci;
}

// ---------------------------------------------------------------------------
// Per-head coupling -> eig (fp32, output #2) and eig_bf (bf16 GEMM operand)
// ---------------------------------------------------------------------------
__global__ __launch_bounds__(256) void coupling_kernel(const float* __restrict__ cr,
                                                       const float* __restrict__ ci,
                                                       const float* __restrict__ coup,
                                                       float* __restrict__ eig,
                                                       __hip_bfloat16* __restrict__ eig_bf) {
    const int b = blockIdx.z, h = blockIdx.y, t0 = blockIdx.x * 256;
    const int tid = threadIdx.x;
    __shared__ float sc[16][16];
    sc[tid >> 4][tid & 15] = coup[h * 256 + tid];
    __syncthreads();
    const int t = t0 + tid;
    float orr[16], oii[16];
#pragma unroll
    for (int j = 0; j < 16; ++j) { orr[j] = 0.f; oii[j] = 0.f; }
    for (int k2 = 0; k2 < 16; ++k2) {
        const float vr = cr[((size_t)b * Kn + h * 16 + k2) * Tn + t];
        const float vi = ci[((size_t)b * Kn + h * 16 + k2) * Tn + t];
#pragma unroll
        for (int j = 0; j < 16; ++j) {
            orr[j] += sc[j][k2] * vr;
            oii[j] += sc[j][k2] * vi;
        }
    }
    const size_t base = ((size_t)b * Tn + t) * TWOK + h * 16;
#pragma unroll
    for (int j = 0; j < 16; ++j) {
        eig[base + j] = orr[j];
        eig[base + Kn + j] = oii[j];
        eig_bf[base + j] = __float2bfloat16(orr[j]);
        eig_bf[base + Kn + j] = __float2bfloat16(oii[j]);
    }
}

// ---------------------------------------------------------------------------
extern "C" void kernel_launch(void* const* d_in, const int* in_sizes, int n_in,
                              void* d_out, int out_size, void* d_ws, size_t ws_size,
                              hipStream_t stream) {
    const float* x          = (const float*)d_in[0];
    const float* prev_eig   = (const float*)d_in[1];
    const float* in_proj_w  = (const float*)d_in[2];
    const float* conv_w     = (const float*)d_in[3];
    const float* conv_b     = (const float*)d_in[4];
    const float* mem_gate   = (const float*)d_in[5];
    const float* mem_proj_w = (const float*)d_in[6];
    const float* log_decay  = (const float*)d_in[7];
    const float* frequency  = (const float*)d_in[8];
    const float* coupling   = (const float*)d_in[9];
    const float* out_proj_w = (const float*)d_in[10];
    const float* gate_w     = (const float*)d_in[11];
    const float* gate_b     = (const float*)d_in[12];
    const float* mlp_w1     = (const float*)d_in[13];
    const float* mlp_b1     = (const float*)d_in[14];
    const float* mlp_w2     = (const float*)d_in[15];
    const float* mlp_b2     = (const float*)d_in[16];
    const float* n1_g       = (const float*)d_in[17];
    const float* n1_b       = (const float*)d_in[18];
    const float* n2_g       = (const float*)d_in[19];
    const float* n2_b       = (const float*)d_in[20];

    float* out = (float*)d_out;                     // x2 [16384,1024]
    float* eig = out + (size_t)NROW * Dn;           // eig [16384,256] fp32

    // Workspace layout (byte offsets into 256 MiB), with lifetime-based aliasing.
    char* wsb = (char*)d_ws;
    const size_t MB = 1 << 20;
    float* x1    = (float*)(wsb + 0);               // fp32 64MiB, live step8..end
    float* beta  = (float*)(wsb + 0);               //  aliases x1 pre-8: live 2-4
    float* mgp   = (float*)(wsb + 16 * MB);         //  live 3-4
    float* ur    = (float*)(wsb + 32 * MB);         //  live 4-5
    float* ui    = (float*)(wsb + 40 * MB);
    float* crb   = (float*)(wsb + 48 * MB);         //  live 5-6
    float* cib   = (float*)(wsb + 56 * MB);
    __hip_bfloat16* h1      = (__hip_bfloat16*)(wsb + 64 * MB);   // 64MiB, live step10
    __hip_bfloat16* o_bf    = (__hip_bfloat16*)(wsb + 64 * MB);   //  aliases h1: live 7-8
    __hip_bfloat16* eig_bf  = (__hip_bfloat16*)(wsb + 96 * MB);   //  live 6-7
    __hip_bfloat16* peig_bf = (__hip_bfloat16*)(wsb + 104 * MB);  //  live 0-3
    __hip_bfloat16* xn_bf   = (__hip_bfloat16*)(wsb + 128 * MB);  // live 1-8
    __hip_bfloat16* y_bf    = (__hip_bfloat16*)(wsb + 160 * MB);  // live 9-10
    __hip_bfloat16* w1_bf   = (__hip_bfloat16*)(wsb + 192 * MB);
    __hip_bfloat16* w2_bf   = (__hip_bfloat16*)(wsb + 200 * MB);
    __hip_bfloat16* gate_bf = (__hip_bfloat16*)(wsb + 208 * MB);
    __hip_bfloat16* inpj_bf = (__hip_bfloat16*)(wsb + 210 * MB);
    __hip_bfloat16* outpj_bf= (__hip_bfloat16*)(wsb + 210 * MB + 512 * 1024);
    __hip_bfloat16* mempj_bf= (__hip_bfloat16*)(wsb + 211 * MB);

    // 0) weight/activation bf16 casts (re-done every call; ws is re-poisoned)
    auto cvt = [&](const float* src, __hip_bfloat16* dst, int n) {
        f2bf_kernel<<<dim3((n / 4 + 255) / 256), dim3(256), 0, stream>>>(src, dst, n);
    };
    cvt(in_proj_w,  inpj_bf,  TWOK * Dn);
    cvt(mem_proj_w, mempj_bf, TWOK * TWOK);
    cvt(out_proj_w, outpj_bf, Dn * TWOK);
    cvt(gate_w,     gate_bf,  Dn * Dn);
    cvt(mlp_w1,     w1_bf,    Mmlp * Dn);
    cvt(mlp_w2,     w2_bf,    Dn * Mmlp);
    cvt(prev_eig,   peig_bf,  NROW * TWOK);

    // 1) xn = LN1(x) -> bf16
    ln_kernel<<<dim3(NROW), dim3(256), 0, stream>>>(x, n1_g, n1_b, xn_bf);
    // 2) beta = xn @ in_proj^T  [16384,256] fp32
    gemm_bf<0, float><<<dim3(2, 128), dim3(256), 0, stream>>>(
        (const ushort*)xn_bf, (const ushort*)inpj_bf, beta, NROW, TWOK, Dn,
        nullptr, nullptr, nullptr);
    // 3) mgp = sigmoid(mem_gate) * (prev_eig @ mem_proj^T)
    gemm_bf<1, float><<<dim3(2, 128), dim3(256), 0, stream>>>(
        (const ushort*)peig_bf, (const ushort*)mempj_bf, mgp, NROW, TWOK, TWOK,
        mem_gate, nullptr, nullptr);
    // 4) conv + SiLU + mem inject -> [B,K,T] real/imag
    conv_mem_kernel<<<dim3(8, 128, 4), dim3(256), 0, stream>>>(beta, mgp, conv_w, conv_b, ur, ui);
    // 5) complex FIR
    fir_kernel<<<dim3(16, 128, 4), dim3(256), 0, stream>>>(ur, ui, log_decay, frequency, crb, cib);
    // 6) coupling -> eig (fp32 out) + eig_bf
    coupling_kernel<<<dim3(16, 8, 4), dim3(256), 0, stream>>>(crb, cib, coupling, eig, eig_bf);
    // 7) o = eig @ out_proj^T  -> bf16 [16384,1024]
    gemm_bf<0, __hip_bfloat16><<<dim3(8, 128), dim3(256), 0, stream>>>(
        (const ushort*)eig_bf, (const ushort*)outpj_bf, o_bf, NROW, Dn, TWOK,
        nullptr, nullptr, nullptr);
    // 8) x1 = x + sigmoid(xn @ gate_w^T + gate_b) * o
    gemm_bf<2, float><<<dim3(8, 128), dim3(256), 0, stream>>>(
        (const ushort*)xn_bf, (const ushort*)gate_bf, x1, NROW, Dn, Dn,
        gate_b, x, o_bf);
    // 9) y = LN2(x1) -> bf16
    ln_kernel<<<dim3(NROW), dim3(256), 0, stream>>>(x1, n2_g, n2_b, y_bf);
    // 10) MLP, 2 row-chunks of 8192: x2 = x1 + silu(y@w1^T+b1)@w2^T + b2
    for (int ck = 0; ck < 2; ++ck) {
        const size_t roff = (size_t)ck * 8192 * Dn;
        gemm_bf<3, __hip_bfloat16><<<dim3(32, 64), dim3(256), 0, stream>>>(
            (const ushort*)(y_bf + roff), (const ushort*)w1_bf, h1, 8192, Mmlp, Dn,
            mlp_b1, nullptr, nullptr);
        gemm_bf<4, float><<<dim3(8, 64), dim3(256), 0, stream>>>(
            (const ushort*)h1, (const ushort*)w2_bf, out + roff, 8192, Dn, Mmlp,
            mlp_b2, x1 + roff, nullptr);
    }
}

// Round 3
// 809.055 us; speedup vs baseline: 5.4638x; 1.1360x over previous
//
#include <hip/hip_runtime.h>
#include <hip/hip_bf16.h>
#include <math.h>

// Problem constants
#define Bn 4
#define Tn 4096
#define Dn 1024
#define Kn 128
#define TWOK 256
#define Hn 8
#define Mmlp 4096
#define NROW (Bn * Tn)          // 16384
#define TAPS 16                 // |lambda| <= 0.232 -> tap-16 residual ~1e-9

typedef __attribute__((ext_vector_type(8))) short bf16x8;   // 8 bf16 = 4 VGPRs
typedef __attribute__((ext_vector_type(4))) float floatx4;  // MFMA accumulator

__device__ __forceinline__ float sigmoidf_(float x) { return 1.f / (1.f + expf(-x)); }

// ---------------------------------------------------------------------------
// fp32 -> bf16 cast
// ---------------------------------------------------------------------------
__global__ __launch_bounds__(256) void f2bf_kernel(const float* __restrict__ in,
                                                   __hip_bfloat16* __restrict__ out,
                                                   int n) {
    const int i = (blockIdx.x * 256 + threadIdx.x) * 4;
    if (i >= n) return;
    const float4 v = *(const float4*)(in + i);
    out[i + 0] = __float2bfloat16(v.x);
    out[i + 1] = __float2bfloat16(v.y);
    out[i + 2] = __float2bfloat16(v.z);
    out[i + 3] = __float2bfloat16(v.w);
}

// ---------------------------------------------------------------------------
// LayerNorm (D=1024, 256 thr) -> bf16
// ---------------------------------------------------------------------------
__global__ __launch_bounds__(256) void ln_kernel(const float* __restrict__ x,
                                                 const float* __restrict__ g,
                                                 const float* __restrict__ b,
                                                 __hip_bfloat16* __restrict__ out) {
    const int row = blockIdx.x;
    const float4* xr = (const float4*)(x + (size_t)row * Dn);
    float4 v = xr[threadIdx.x];
    float s = v.x + v.y + v.z + v.w;
    float ss = v.x * v.x + v.y * v.y + v.z * v.z + v.w * v.w;
    for (int off = 32; off; off >>= 1) {
        s += __shfl_down(s, off);
        ss += __shfl_down(ss, off);
    }
    __shared__ float rs[4], rss[4];
    const int wv = threadIdx.x >> 6, ln = threadIdx.x & 63;
    if (ln == 0) { rs[wv] = s; rss[wv] = ss; }
    __syncthreads();
    s = rs[0] + rs[1] + rs[2] + rs[3];
    ss = rss[0] + rss[1] + rss[2] + rss[3];
    const float mean = s * (1.f / Dn);
    const float var = ss * (1.f / Dn) - mean * mean;
    const float inv = rsqrtf(var + 1e-5f);
    const float4 gg = ((const float4*)g)[threadIdx.x];
    const float4 bb = ((const float4*)b)[threadIdx.x];
    __hip_bfloat16* op = out + (size_t)row * Dn + threadIdx.x * 4;
    op[0] = __float2bfloat16((v.x - mean) * inv * gg.x + bb.x);
    op[1] = __float2bfloat16((v.y - mean) * inv * gg.y + bb.y);
    op[2] = __float2bfloat16((v.z - mean) * inv * gg.z + bb.z);
    op[3] = __float2bfloat16((v.w - mean) * inv * gg.w + bb.w);
}

// ---------------------------------------------------------------------------
// bf16 MFMA GEMM: C[M,N] = A[M,K] @ B[N,K]^T.  128x128 tile, BK=32, 4 waves.
// __launch_bounds__(256,4): force arch VGPR <= 64 so arch+64 AGPR fits the
// 128-reg slot -> 4 blocks/CU (was 2 at 88+64 -> 256-slot).
// ---------------------------------------------------------------------------
template <int EPI, typename CT>
__global__ __launch_bounds__(256, 4) void gemm_bf(const ushort* __restrict__ A,
                                                  const ushort* __restrict__ B,
                                                  CT* __restrict__ C,
                                                  int M, int N, int Kd,
                                                  const float* __restrict__ bias,
                                                  const float* __restrict__ aux1,
                                                  const __hip_bfloat16* __restrict__ aux2) {
    __shared__ ushort As[128 * 32];   // contiguous (global_load_lds requirement)
    __shared__ ushort Bs[128 * 32];
    const int tid = threadIdx.x;
    const int m0 = blockIdx.y * 128, n0 = blockIdx.x * 128;
    const int wave = tid >> 6, lane = tid & 63;
    const int wm = wave >> 1, wn = wave & 1;
    const int mlane = lane & 15, quad = lane >> 4;

    floatx4 acc[4][4] = {};

    const ushort* Ap = A + (size_t)m0 * Kd;
    const ushort* Bp = B + (size_t)n0 * Kd;

    for (int k0 = 0; k0 < Kd; k0 += 32) {
#pragma unroll
        for (int q = 0; q < 2; ++q) {
            const int c = q * 256 + tid;          // 16B chunk: row=c>>2, kcol=(c&3)*8
            const int row = c >> 2, kc = (c & 3) * 8;
            __builtin_amdgcn_global_load_lds(
                (const __attribute__((address_space(1))) void*)(Ap + (size_t)row * Kd + k0 + kc),
                (__attribute__((address_space(3))) void*)(As + c * 8), 16, 0, 0);
            __builtin_amdgcn_global_load_lds(
                (const __attribute__((address_space(1))) void*)(Bp + (size_t)row * Kd + k0 + kc),
                (__attribute__((address_space(3))) void*)(Bs + c * 8), 16, 0, 0);
        }
        __syncthreads();

        bf16x8 af[4], bfr[4];
#pragma unroll
        for (int t = 0; t < 4; ++t) {
            af[t]  = *(const bf16x8*)&As[(wm * 64 + t * 16 + mlane) * 32 + quad * 8];
            bfr[t] = *(const bf16x8*)&Bs[(wn * 64 + t * 16 + mlane) * 32 + quad * 8];
        }
#pragma unroll
        for (int i = 0; i < 4; ++i)
#pragma unroll
            for (int j = 0; j < 4; ++j)
                acc[i][j] = __builtin_amdgcn_mfma_f32_16x16x32_bf16(af[i], bfr[j], acc[i][j], 0, 0, 0);
        __syncthreads();
    }

    float s_pre = 0.f;
    if constexpr (EPI == 1) s_pre = sigmoidf_(bias[0]);

    const int cbase = n0 + wn * 64 + mlane;
#pragma unroll
    for (int i = 0; i < 4; ++i) {
#pragma unroll
        for (int r = 0; r < 4; ++r) {
            const int row = m0 + wm * 64 + i * 16 + quad * 4 + r;
            const size_t ro = (size_t)row * N;
#pragma unroll
            for (int j = 0; j < 4; ++j) {
                const int col = cbase + j * 16;
                const float a = acc[i][j][r];
                float o;
                if constexpr (EPI == 0) {
                    o = a;
                } else if constexpr (EPI == 1) {
                    o = s_pre * a;
                } else if constexpr (EPI == 2) {
                    o = aux1[ro + col] + sigmoidf_(a + bias[col]) * __bfloat162float(aux2[ro + col]);
                } else if constexpr (EPI == 3) {
                    const float t = a + bias[col];
                    o = t * sigmoidf_(t);
                } else {
                    o = a + bias[col] + aux1[ro + col];
                }
                if constexpr (__is_same(CT, float)) C[ro + col] = o;
                else                                C[ro + col] = __float2bfloat16(o);
            }
        }
    }
}

// ---------------------------------------------------------------------------
// Fused: depthwise causal conv(4) + bias + SiLU + memory injection + 16-tap
// complex FIR + per-head coupling -> eig (fp32 out) + eig_bf (bf16 operand).
// Block handles (b, h, 256-t chunk) over 32 channels (16 real + 16 imag).
// ---------------------------------------------------------------------------
#define TCH 256
#define BROWS (TCH + TAPS + 2)   // beta rows: t in [t0-18, t0+255] = 274
#define UROWS (TCH + TAPS - 1)   // u rows:    t in [t0-15, t0+255] = 271

__global__ __launch_bounds__(256) void cfc_kernel(const float* __restrict__ beta,
                                                  const float* __restrict__ mgp,
                                                  const float* __restrict__ conv_w,
                                                  const float* __restrict__ conv_b,
                                                  const float* __restrict__ log_decay,
                                                  const float* __restrict__ freq,
                                                  const float* __restrict__ coup,
                                                  float* __restrict__ eig,
                                                  __hip_bfloat16* __restrict__ eig_bf) {
    const int b = blockIdx.z, h = blockIdx.y, t0 = blockIdx.x * TCH;
    const int tid = threadIdx.x;

    __shared__ float sbeta[BROWS * 32];       // col cg: cg<16 -> real ch, else imag
    __shared__ float su[UROWS * 33];          // pad 33: FIR reads col-major
    __shared__ float str[16 * TAPS], sti[16 * TAPS];
    __shared__ float scoup[16 * 16];
    __shared__ float scw[32 * 4], scb[32];

    // channel map: local cg -> global channel in [0,256)
    auto chan = [&](int cg) { return (cg < 16) ? (h * 16 + cg) : (128 + h * 16 + cg - 16); };

    // ---- stage beta tile [t0-18, t0+255] and mgp tile [t0-15, t0+255]
    for (int idx = tid; idx < BROWS * 32; idx += 256) {
        const int r = idx >> 5, cg = idx & 31;
        const int t = t0 - (TAPS + 2) + r;
        sbeta[idx] = (t >= 0) ? beta[((size_t)b * Tn + t) * TWOK + chan(cg)] : 0.f;
    }
    for (int idx = tid; idx < UROWS * 32; idx += 256) {
        const int r = idx >> 5, cg = idx & 31;
        const int t = t0 - (TAPS - 1) + r;
        su[r * 33 + cg] = (t >= 0) ? mgp[((size_t)b * Tn + t) * TWOK + chan(cg)] : 0.f;
    }
    // ---- conv weights, coupling, FIR taps
    if (tid < 128) scw[tid] = conv_w[chan(tid >> 2) * 4 + (tid & 3)];
    else if (tid < 160) scb[tid - 128] = conv_b[chan(tid - 128)];
    scoup[tid] = coup[h * 256 + tid];
    {
        const int k = tid >> 4, d = tid & (TAPS - 1);   // TAPS=16: tid covers all (k,d)
        const float mag = sigmoidf_(log_decay[h * 16 + k]);
        const float f = freq[h * 16 + k];
        const float p = powf(mag, (float)d);
        str[k * TAPS + d] = p * cosf(d * f);
        sti[k * TAPS + d] = p * sinf(d * f);
    }
    __syncthreads();

    // ---- u = silu(conv(beta)+cb) + mgp, in place over su
    for (int idx = tid; idx < UROWS * 32; idx += 256) {
        const int r = idx >> 5, cg = idx & 31;
        const int rb = r + 3;                 // sbeta row of time t (3 taps back exist)
        float v = sbeta[(rb - 3) * 32 + cg] * scw[cg * 4 + 0] +
                  sbeta[(rb - 2) * 32 + cg] * scw[cg * 4 + 1] +
                  sbeta[(rb - 1) * 32 + cg] * scw[cg * 4 + 2] +
                  sbeta[(rb - 0) * 32 + cg] * scw[cg * 4 + 3] + scb[cg];
        v = v * sigmoidf_(v);
        su[r * 33 + cg] += v;                 // += mgp already there
    }
    __syncthreads();

    // ---- FIR (16 taps) + coupling for t = t0 + tid
    const int ru = tid + (TAPS - 1);          // su row of time t
    float orr[16], oii[16];
#pragma unroll
    for (int j = 0; j < 16; ++j) { orr[j] = 0.f; oii[j] = 0.f; }
#pragma unroll 4
    for (int k = 0; k < 16; ++k) {
        float accr = 0.f, acci = 0.f;
#pragma unroll
        for (int d = 0; d < TAPS; ++d) {
            const float ur = su[(ru - d) * 33 + k];
            const float ui = su[(ru - d) * 33 + 16 + k];
            const float lr = str[k * TAPS + d], li = sti[k * TAPS + d];
            accr += lr * ur - li * ui;
            acci += lr * ui + li * ur;
        }
#pragma unroll
        for (int j = 0; j < 16; ++j) {
            orr[j] += scoup[j * 16 + k] * accr;
            oii[j] += scoup[j * 16 + k] * acci;
        }
    }
    const size_t base = ((size_t)b * Tn + t0 + tid) * TWOK + h * 16;
    float4* er = (float4*)(eig + base);
    float4* ei = (float4*)(eig + base + Kn);
#pragma unroll
    for (int q = 0; q < 4; ++q) {
        er[q] = make_float4(orr[4 * q], orr[4 * q + 1], orr[4 * q + 2], orr[4 * q + 3]);
        ei[q] = make_float4(oii[4 * q], oii[4 * q + 1], oii[4 * q + 2], oii[4 * q + 3]);
    }
#pragma unroll
    for (int j = 0; j < 16; ++j) {
        eig_bf[base + j] = __float2bfloat16(orr[j]);
        eig_bf[base + Kn + j] = __float2bfloat16(oii[j]);
    }
}

// ---------------------------------------------------------------------------
extern "C" void kernel_launch(void* const* d_in, const int* in_sizes, int n_in,
                              void* d_out, int out_size, void* d_ws, size_t ws_size,
                              hipStream_t stream) {
    const float* x          = (const float*)d_in[0];
    const float* prev_eig   = (const float*)d_in[1];
    const float* in_proj_w  = (const float*)d_in[2];
    const float* conv_w     = (const float*)d_in[3];
    const float* conv_b     = (const float*)d_in[4];
    const float* mem_gate   = (const float*)d_in[5];
    const float* mem_proj_w = (const float*)d_in[6];
    const float* log_decay  = (const float*)d_in[7];
    const float* frequency  = (const float*)d_in[8];
    const float* coupling   = (const float*)d_in[9];
    const float* out_proj_w = (const float*)d_in[10];
    const float* gate_w     = (const float*)d_in[11];
    const float* gate_b     = (const float*)d_in[12];
    const float* mlp_w1     = (const float*)d_in[13];
    const float* mlp_b1     = (const float*)d_in[14];
    const float* mlp_w2     = (const float*)d_in[15];
    const float* mlp_b2     = (const float*)d_in[16];
    const float* n1_g       = (const float*)d_in[17];
    const float* n1_b       = (const float*)d_in[18];
    const float* n2_g       = (const float*)d_in[19];
    const float* n2_b       = (const float*)d_in[20];

    float* out = (float*)d_out;                     // x2 [16384,1024]
    float* eig = out + (size_t)NROW * Dn;           // eig [16384,256] fp32

    char* wsb = (char*)d_ws;
    const size_t MB = 1 << 20;
    float* x1    = (float*)(wsb + 0);               // 64MB, live step8..end
    float* beta  = (float*)(wsb + 0);               //  alias, 16MB, live 2-4 (dead pre-x1)
    float* mgp   = (float*)(wsb + 16 * MB);         //  16MB, live 3-4
    __hip_bfloat16* h1      = (__hip_bfloat16*)(wsb + 64 * MB);   // 64MB, step10
    __hip_bfloat16* o_bf    = (__hip_bfloat16*)(wsb + 64 * MB);   //  alias, live 7-8
    __hip_bfloat16* eig_bf  = (__hip_bfloat16*)(wsb + 96 * MB);
    __hip_bfloat16* peig_bf = (__hip_bfloat16*)(wsb + 104 * MB);
    __hip_bfloat16* xn_bf   = (__hip_bfloat16*)(wsb + 128 * MB);
    __hip_bfloat16* y_bf    = (__hip_bfloat16*)(wsb + 160 * MB);
    __hip_bfloat16* w1_bf   = (__hip_bfloat16*)(wsb + 192 * MB);
    __hip_bfloat16* w2_bf   = (__hip_bfloat16*)(wsb + 200 * MB);
    __hip_bfloat16* gate_bf = (__hip_bfloat16*)(wsb + 208 * MB);
    __hip_bfloat16* inpj_bf = (__hip_bfloat16*)(wsb + 210 * MB);
    __hip_bfloat16* outpj_bf= (__hip_bfloat16*)(wsb + 210 * MB + 512 * 1024);
    __hip_bfloat16* mempj_bf= (__hip_bfloat16*)(wsb + 211 * MB);

    auto cvt = [&](const float* src, __hip_bfloat16* dst, int n) {
        f2bf_kernel<<<dim3((n / 4 + 255) / 256), dim3(256), 0, stream>>>(src, dst, n);
    };
    cvt(in_proj_w,  inpj_bf,  TWOK * Dn);
    cvt(mem_proj_w, mempj_bf, TWOK * TWOK);
    cvt(out_proj_w, outpj_bf, Dn * TWOK);
    cvt(gate_w,     gate_bf,  Dn * Dn);
    cvt(mlp_w1,     w1_bf,    Mmlp * Dn);
    cvt(mlp_w2,     w2_bf,    Dn * Mmlp);
    cvt(prev_eig,   peig_bf,  NROW * TWOK);

    // 1) xn = LN1(x) -> bf16
    ln_kernel<<<dim3(NROW), dim3(256), 0, stream>>>(x, n1_g, n1_b, xn_bf);
    // 2) beta = xn @ in_proj^T  [16384,256] fp32
    gemm_bf<0, float><<<dim3(2, 128), dim3(256), 0, stream>>>(
        (const ushort*)xn_bf, (const ushort*)inpj_bf, beta, NROW, TWOK, Dn,
        nullptr, nullptr, nullptr);
    // 3) mgp = sigmoid(mem_gate) * (prev_eig @ mem_proj^T)
    gemm_bf<1, float><<<dim3(2, 128), dim3(256), 0, stream>>>(
        (const ushort*)peig_bf, (const ushort*)mempj_bf, mgp, NROW, TWOK, TWOK,
        mem_gate, nullptr, nullptr);
    // 4-6) fused conv + SiLU + mem + FIR + coupling -> eig, eig_bf
    cfc_kernel<<<dim3(Tn / TCH, Hn, Bn), dim3(256), 0, stream>>>(
        beta, mgp, conv_w, conv_b, log_decay, frequency, coupling, eig, eig_bf);
    // 7) o = eig @ out_proj^T -> bf16 [16384,1024]
    gemm_bf<0, __hip_bfloat16><<<dim3(8, 128), dim3(256), 0, stream>>>(
        (const ushort*)eig_bf, (const ushort*)outpj_bf, o_bf, NROW, Dn, TWOK,
        nullptr, nullptr, nullptr);
    // 8) x1 = x + sigmoid(xn @ gate_w^T + gate_b) * o
    gemm_bf<2, float><<<dim3(8, 128), dim3(256), 0, stream>>>(
        (const ushort*)xn_bf, (const ushort*)gate_bf, x1, NROW, Dn, Dn,
        gate_b, x, o_bf);
    // 9) y = LN2(x1) -> bf16
    ln_kernel<<<dim3(NROW), dim3(256), 0, stream>>>(x1, n2_g, n2_b, y_bf);
    // 10) MLP, 2 row-chunks of 8192
    for (int ck = 0; ck < 2; ++ck) {
        const size_t roff = (size_t)ck * 8192 * Dn;
        gemm_bf<3, __hip_bfloat16><<<dim3(32, 64), dim3(256), 0, stream>>>(
            (const ushort*)(y_bf + roff), (const ushort*)w1_bf, h1, 8192, Mmlp, Dn,
            mlp_b1, nullptr, nullptr);
        gemm_bf<4, float><<<dim3(8, 64), dim3(256), 0, stream>>>(
            (const ushort*)h1, (const ushort*)w2_bf, out + roff, 8192, Dn, Mmlp,
            mlp_b2, x1 + roff, nullptr);
    }
}

// Round 4
// 785.401 us; speedup vs baseline: 5.6283x; 1.0301x over previous
//
#include <hip/hip_runtime.h>
#include <hip/hip_bf16.h>
#include <math.h>

// Problem constants
#define Bn 4
#define Tn 4096
#define Dn 1024
#define Kn 128
#define TWOK 256
#define Hn 8
#define Mmlp 4096
#define NROW (Bn * Tn)          // 16384
#define TAPS 16                 // |lambda| <= 0.232 -> tap-16 residual ~1e-9

typedef __attribute__((ext_vector_type(8))) short bf16x8;   // 8 bf16 = 4 VGPRs
typedef __attribute__((ext_vector_type(4))) float floatx4;  // MFMA accumulator

__device__ __forceinline__ float sigmoidf_(float x) { return 1.f / (1.f + expf(-x)); }

// ---------------------------------------------------------------------------
// fp32 -> bf16 cast
// ---------------------------------------------------------------------------
__global__ __launch_bounds__(256) void f2bf_kernel(const float* __restrict__ in,
                                                   __hip_bfloat16* __restrict__ out,
                                                   int n) {
    const int i = (blockIdx.x * 256 + threadIdx.x) * 4;
    if (i >= n) return;
    const float4 v = *(const float4*)(in + i);
    out[i + 0] = __float2bfloat16(v.x);
    out[i + 1] = __float2bfloat16(v.y);
    out[i + 2] = __float2bfloat16(v.z);
    out[i + 3] = __float2bfloat16(v.w);
}

// ---------------------------------------------------------------------------
// LayerNorm (D=1024, 256 thr) -> bf16
// ---------------------------------------------------------------------------
__global__ __launch_bounds__(256) void ln_kernel(const float* __restrict__ x,
                                                 const float* __restrict__ g,
                                                 const float* __restrict__ b,
                                                 __hip_bfloat16* __restrict__ out) {
    const int row = blockIdx.x;
    const float4* xr = (const float4*)(x + (size_t)row * Dn);
    float4 v = xr[threadIdx.x];
    float s = v.x + v.y + v.z + v.w;
    float ss = v.x * v.x + v.y * v.y + v.z * v.z + v.w * v.w;
    for (int off = 32; off; off >>= 1) {
        s += __shfl_down(s, off);
        ss += __shfl_down(ss, off);
    }
    __shared__ float rs[4], rss[4];
    const int wv = threadIdx.x >> 6, ln = threadIdx.x & 63;
    if (ln == 0) { rs[wv] = s; rss[wv] = ss; }
    __syncthreads();
    s = rs[0] + rs[1] + rs[2] + rs[3];
    ss = rss[0] + rss[1] + rss[2] + rss[3];
    const float mean = s * (1.f / Dn);
    const float var = ss * (1.f / Dn) - mean * mean;
    const float inv = rsqrtf(var + 1e-5f);
    const float4 gg = ((const float4*)g)[threadIdx.x];
    const float4 bb = ((const float4*)b)[threadIdx.x];
    __hip_bfloat16* op = out + (size_t)row * Dn + threadIdx.x * 4;
    op[0] = __float2bfloat16((v.x - mean) * inv * gg.x + bb.x);
    op[1] = __float2bfloat16((v.y - mean) * inv * gg.y + bb.y);
    op[2] = __float2bfloat16((v.z - mean) * inv * gg.z + bb.z);
    op[3] = __float2bfloat16((v.w - mean) * inv * gg.w + bb.w);
}

// ---------------------------------------------------------------------------
// bf16 MFMA GEMM: C[M,N] = A[M,K] @ B[N,K]^T.  128x128 tile, BK=32, 4 waves.
// XCD-aware tile remap: dispatch round-robins flat bid across 8 XCDs, so give
// each XCD a contiguous x-fastest strip of tiles -> A-stripe reuse stays in
// one XCD's L2 (round-3 profile: FETCH 290MB vs 104MB unique = cross-XCD
// A-stripe duplication).
// Epilogues: 0 none | 1 C=sigmoid(bias[0])*acc | 2 C=aux1+sig(acc+bias)*aux2
//            3 C=silu(acc+bias) | 4 C=acc+bias+aux1
//            5 C=aux1 + sig(acc+bias)*acc2 where acc2 = A2@B2^T (fused
//              out_proj+gate; needs 128 acc regs -> min-waves 2)
// ---------------------------------------------------------------------------
template <int EPI, typename CT>
__global__ __launch_bounds__(256, EPI == 5 ? 2 : 4)
void gemm_bf(const ushort* __restrict__ A,
             const ushort* __restrict__ B,
             CT* __restrict__ C,
             int M, int N, int Kd,
             const float* __restrict__ bias,
             const float* __restrict__ aux1,
             const __hip_bfloat16* __restrict__ aux2,
             const ushort* __restrict__ A2, const ushort* __restrict__ B2, int Kd2) {
    __shared__ ushort As[128 * 32];   // contiguous (global_load_lds requirement)
    __shared__ ushort Bs[128 * 32];
    const int tid = threadIdx.x;
    const int nbx = gridDim.x;
    const int nblk = nbx * gridDim.y;
    int bid = blockIdx.y * nbx + blockIdx.x;
    if ((nblk & 7) == 0)
        bid = (bid & 7) * (nblk >> 3) + (bid >> 3);   // XCD strip remap
    const int m0 = (bid / nbx) * 128, n0 = (bid % nbx) * 128;
    const int wave = tid >> 6, lane = tid & 63;
    const int wm = wave >> 1, wn = wave & 1;
    const int mlane = lane & 15, quad = lane >> 4;

    floatx4 acc[4][4] = {};

    {
        const ushort* Ap = A + (size_t)m0 * Kd;
        const ushort* Bp = B + (size_t)n0 * Kd;
        for (int k0 = 0; k0 < Kd; k0 += 32) {
#pragma unroll
            for (int q = 0; q < 2; ++q) {
                const int c = q * 256 + tid;          // 16B chunk: row=c>>2, kcol=(c&3)*8
                const int row = c >> 2, kc = (c & 3) * 8;
                __builtin_amdgcn_global_load_lds(
                    (const __attribute__((address_space(1))) void*)(Ap + (size_t)row * Kd + k0 + kc),
                    (__attribute__((address_space(3))) void*)(As + c * 8), 16, 0, 0);
                __builtin_amdgcn_global_load_lds(
                    (const __attribute__((address_space(1))) void*)(Bp + (size_t)row * Kd + k0 + kc),
                    (__attribute__((address_space(3))) void*)(Bs + c * 8), 16, 0, 0);
            }
            __syncthreads();
            bf16x8 af[4], bfr[4];
#pragma unroll
            for (int t = 0; t < 4; ++t) {
                af[t]  = *(const bf16x8*)&As[(wm * 64 + t * 16 + mlane) * 32 + quad * 8];
                bfr[t] = *(const bf16x8*)&Bs[(wn * 64 + t * 16 + mlane) * 32 + quad * 8];
            }
#pragma unroll
            for (int i = 0; i < 4; ++i)
#pragma unroll
                for (int j = 0; j < 4; ++j)
                    acc[i][j] = __builtin_amdgcn_mfma_f32_16x16x32_bf16(af[i], bfr[j], acc[i][j], 0, 0, 0);
            __syncthreads();
        }
    }

    // Optional second GEMM (EPI==5): acc2 = A2[M,Kd2] @ B2[N,Kd2]^T
    floatx4 acc2[EPI == 5 ? 4 : 1][EPI == 5 ? 4 : 1] = {};
    if constexpr (EPI == 5) {
        const ushort* Ap = A2 + (size_t)m0 * Kd2;
        const ushort* Bp = B2 + (size_t)n0 * Kd2;
        for (int k0 = 0; k0 < Kd2; k0 += 32) {
#pragma unroll
            for (int q = 0; q < 2; ++q) {
                const int c = q * 256 + tid;
                const int row = c >> 2, kc = (c & 3) * 8;
                __builtin_amdgcn_global_load_lds(
                    (const __attribute__((address_space(1))) void*)(Ap + (size_t)row * Kd2 + k0 + kc),
                    (__attribute__((address_space(3))) void*)(As + c * 8), 16, 0, 0);
                __builtin_amdgcn_global_load_lds(
                    (const __attribute__((address_space(1))) void*)(Bp + (size_t)row * Kd2 + k0 + kc),
                    (__attribute__((address_space(3))) void*)(Bs + c * 8), 16, 0, 0);
            }
            __syncthreads();
            bf16x8 af[4], bfr[4];
#pragma unroll
            for (int t = 0; t < 4; ++t) {
                af[t]  = *(const bf16x8*)&As[(wm * 64 + t * 16 + mlane) * 32 + quad * 8];
                bfr[t] = *(const bf16x8*)&Bs[(wn * 64 + t * 16 + mlane) * 32 + quad * 8];
            }
#pragma unroll
            for (int i = 0; i < 4; ++i)
#pragma unroll
                for (int j = 0; j < 4; ++j)
                    acc2[i][j] = __builtin_amdgcn_mfma_f32_16x16x32_bf16(af[i], bfr[j], acc2[i][j], 0, 0, 0);
            __syncthreads();
        }
    }

    float s_pre = 0.f;
    if constexpr (EPI == 1) s_pre = sigmoidf_(bias[0]);

    const int cbase = n0 + wn * 64 + mlane;
#pragma unroll
    for (int i = 0; i < 4; ++i) {
#pragma unroll
        for (int r = 0; r < 4; ++r) {
            const int row = m0 + wm * 64 + i * 16 + quad * 4 + r;
            const size_t ro = (size_t)row * N;
#pragma unroll
            for (int j = 0; j < 4; ++j) {
                const int col = cbase + j * 16;
                const float a = acc[i][j][r];
                float o;
                if constexpr (EPI == 0) {
                    o = a;
                } else if constexpr (EPI == 1) {
                    o = s_pre * a;
                } else if constexpr (EPI == 2) {
                    o = aux1[ro + col] + sigmoidf_(a + bias[col]) * __bfloat162float(aux2[ro + col]);
                } else if constexpr (EPI == 3) {
                    const float t = a + bias[col];
                    o = t * sigmoidf_(t);
                } else if constexpr (EPI == 4) {
                    o = a + bias[col] + aux1[ro + col];
                } else {  // 5: x1 = x + sigmoid(gate)*o
                    o = aux1[ro + col] + sigmoidf_(a + bias[col]) * acc2[i][j][r];
                }
                if constexpr (__is_same(CT, float)) C[ro + col] = o;
                else                                C[ro + col] = __float2bfloat16(o);
            }
        }
    }
}

// ---------------------------------------------------------------------------
// Fused: depthwise causal conv(4) + bias + SiLU + memory injection + 16-tap
// complex FIR + per-head coupling -> eig (fp32 out) + eig_bf (bf16 operand).
// ---------------------------------------------------------------------------
#define TCH 256
#define BROWS (TCH + TAPS + 2)   // beta rows: t in [t0-18, t0+255] = 274
#define UROWS (TCH + TAPS - 1)   // u rows:    t in [t0-15, t0+255] = 271

__global__ __launch_bounds__(256) void cfc_kernel(const float* __restrict__ beta,
                                                  const float* __restrict__ mgp,
                                                  const float* __restrict__ conv_w,
                                                  const float* __restrict__ conv_b,
                                                  const float* __restrict__ log_decay,
                                                  const float* __restrict__ freq,
                                                  const float* __restrict__ coup,
                                                  float* __restrict__ eig,
                                                  __hip_bfloat16* __restrict__ eig_bf) {
    const int b = blockIdx.z, h = blockIdx.y, t0 = blockIdx.x * TCH;
    const int tid = threadIdx.x;

    __shared__ float sbeta[BROWS * 32];       // col cg: cg<16 -> real ch, else imag
    __shared__ float su[UROWS * 33];
    __shared__ float str[16 * TAPS], sti[16 * TAPS];
    __shared__ float scoup[16 * 16];
    __shared__ float scw[32 * 4], scb[32];

    auto chan = [&](int cg) { return (cg < 16) ? (h * 16 + cg) : (128 + h * 16 + cg - 16); };

    for (int idx = tid; idx < BROWS * 32; idx += 256) {
        const int r = idx >> 5, cg = idx & 31;
        const int t = t0 - (TAPS + 2) + r;
        sbeta[idx] = (t >= 0) ? beta[((size_t)b * Tn + t) * TWOK + chan(cg)] : 0.f;
    }
    for (int idx = tid; idx < UROWS * 32; idx += 256) {
        const int r = idx >> 5, cg = idx & 31;
        const int t = t0 - (TAPS - 1) + r;
        su[r * 33 + cg] = (t >= 0) ? mgp[((size_t)b * Tn + t) * TWOK + chan(cg)] : 0.f;
    }
    if (tid < 128) scw[tid] = conv_w[chan(tid >> 2) * 4 + (tid & 3)];
    else if (tid < 160) scb[tid - 128] = conv_b[chan(tid - 128)];
    scoup[tid] = coup[h * 256 + tid];
    {
        const int k = tid >> 4, d = tid & (TAPS - 1);
        const float mag = sigmoidf_(log_decay[h * 16 + k]);
        const float f = freq[h * 16 + k];
        const float p = powf(mag, (float)d);
        str[k * TAPS + d] = p * cosf(d * f);
        sti[k * TAPS + d] = p * sinf(d * f);
    }
    __syncthreads();

    for (int idx = tid; idx < UROWS * 32; idx += 256) {
        const int r = idx >> 5, cg = idx & 31;
        const int rb = r + 3;
        float v = sbeta[(rb - 3) * 32 + cg] * scw[cg * 4 + 0] +
                  sbeta[(rb - 2) * 32 + cg] * scw[cg * 4 + 1] +
                  sbeta[(rb - 1) * 32 + cg] * scw[cg * 4 + 2] +
                  sbeta[(rb - 0) * 32 + cg] * scw[cg * 4 + 3] + scb[cg];
        v = v * sigmoidf_(v);
        su[r * 33 + cg] += v;
    }
    __syncthreads();

    const int ru = tid + (TAPS - 1);
    float orr[16], oii[16];
#pragma unroll
    for (int j = 0; j < 16; ++j) { orr[j] = 0.f; oii[j] = 0.f; }
#pragma unroll 4
    for (int k = 0; k < 16; ++k) {
        float accr = 0.f, acci = 0.f;
#pragma unroll
        for (int d = 0; d < TAPS; ++d) {
            const float ur = su[(ru - d) * 33 + k];
            const float ui = su[(ru - d) * 33 + 16 + k];
            const float lr = str[k * TAPS + d], li = sti[k * TAPS + d];
            accr += lr * ur - li * ui;
            acci += lr * ui + li * ur;
        }
#pragma unroll
        for (int j = 0; j < 16; ++j) {
            orr[j] += scoup[j * 16 + k] * accr;
            oii[j] += scoup[j * 16 + k] * acci;
        }
    }
    const size_t base = ((size_t)b * Tn + t0 + tid) * TWOK + h * 16;
    float4* er = (float4*)(eig + base);
    float4* ei = (float4*)(eig + base + Kn);
#pragma unroll
    for (int q = 0; q < 4; ++q) {
        er[q] = make_float4(orr[4 * q], orr[4 * q + 1], orr[4 * q + 2], orr[4 * q + 3]);
        ei[q] = make_float4(oii[4 * q], oii[4 * q + 1], oii[4 * q + 2], oii[4 * q + 3]);
    }
#pragma unroll
    for (int j = 0; j < 16; ++j) {
        eig_bf[base + j] = __float2bfloat16(orr[j]);
        eig_bf[base + Kn + j] = __float2bfloat16(oii[j]);
    }
}

// ---------------------------------------------------------------------------
extern "C" void kernel_launch(void* const* d_in, const int* in_sizes, int n_in,
                              void* d_out, int out_size, void* d_ws, size_t ws_size,
                              hipStream_t stream) {
    const float* x          = (const float*)d_in[0];
    const float* prev_eig   = (const float*)d_in[1];
    const float* in_proj_w  = (const float*)d_in[2];
    const float* conv_w     = (const float*)d_in[3];
    const float* conv_b     = (const float*)d_in[4];
    const float* mem_gate   = (const float*)d_in[5];
    const float* mem_proj_w = (const float*)d_in[6];
    const float* log_decay  = (const float*)d_in[7];
    const float* frequency  = (const float*)d_in[8];
    const float* coupling   = (const float*)d_in[9];
    const float* out_proj_w = (const float*)d_in[10];
    const float* gate_w     = (const float*)d_in[11];
    const float* gate_b     = (const float*)d_in[12];
    const float* mlp_w1     = (const float*)d_in[13];
    const float* mlp_b1     = (const float*)d_in[14];
    const float* mlp_w2     = (const float*)d_in[15];
    const float* mlp_b2     = (const float*)d_in[16];
    const float* n1_g       = (const float*)d_in[17];
    const float* n1_b       = (const float*)d_in[18];
    const float* n2_g       = (const float*)d_in[19];
    const float* n2_b       = (const float*)d_in[20];

    float* out = (float*)d_out;                     // x2 [16384,1024]
    float* eig = out + (size_t)NROW * Dn;           // eig [16384,256] fp32

    char* wsb = (char*)d_ws;
    const size_t MB = 1 << 20;
    float* x1    = (float*)(wsb + 0);               // 64MB, live step8..end
    float* beta  = (float*)(wsb + 0);               //  alias, live 2-4
    float* mgp   = (float*)(wsb + 16 * MB);         //  live 3-4
    __hip_bfloat16* h1      = (__hip_bfloat16*)(wsb + 64 * MB);   // 64MB, step10
    __hip_bfloat16* eig_bf  = (__hip_bfloat16*)(wsb + 96 * MB);
    __hip_bfloat16* peig_bf = (__hip_bfloat16*)(wsb + 104 * MB);
    __hip_bfloat16* xn_bf   = (__hip_bfloat16*)(wsb + 128 * MB);
    __hip_bfloat16* y_bf    = (__hip_bfloat16*)(wsb + 160 * MB);
    __hip_bfloat16* w1_bf   = (__hip_bfloat16*)(wsb + 192 * MB);
    __hip_bfloat16* w2_bf   = (__hip_bfloat16*)(wsb + 200 * MB);
    __hip_bfloat16* gate_bf = (__hip_bfloat16*)(wsb + 208 * MB);
    __hip_bfloat16* inpj_bf = (__hip_bfloat16*)(wsb + 210 * MB);
    __hip_bfloat16* outpj_bf= (__hip_bfloat16*)(wsb + 210 * MB + 512 * 1024);
    __hip_bfloat16* mempj_bf= (__hip_bfloat16*)(wsb + 211 * MB);

    auto cvt = [&](const float* src, __hip_bfloat16* dst, int n) {
        f2bf_kernel<<<dim3((n / 4 + 255) / 256), dim3(256), 0, stream>>>(src, dst, n);
    };
    cvt(in_proj_w,  inpj_bf,  TWOK * Dn);
    cvt(mem_proj_w, mempj_bf, TWOK * TWOK);
    cvt(out_proj_w, outpj_bf, Dn * TWOK);
    cvt(gate_w,     gate_bf,  Dn * Dn);
    cvt(mlp_w1,     w1_bf,    Mmlp * Dn);
    cvt(mlp_w2,     w2_bf,    Dn * Mmlp);
    cvt(prev_eig,   peig_bf,  NROW * TWOK);

    // 1) xn = LN1(x) -> bf16
    ln_kernel<<<dim3(NROW), dim3(256), 0, stream>>>(x, n1_g, n1_b, xn_bf);
    // 2) beta = xn @ in_proj^T  [16384,256] fp32
    gemm_bf<0, float><<<dim3(2, 128), dim3(256), 0, stream>>>(
        (const ushort*)xn_bf, (const ushort*)inpj_bf, beta, NROW, TWOK, Dn,
        nullptr, nullptr, nullptr, nullptr, nullptr, 0);
    // 3) mgp = sigmoid(mem_gate) * (prev_eig @ mem_proj^T)
    gemm_bf<1, float><<<dim3(2, 128), dim3(256), 0, stream>>>(
        (const ushort*)peig_bf, (const ushort*)mempj_bf, mgp, NROW, TWOK, TWOK,
        mem_gate, nullptr, nullptr, nullptr, nullptr, 0);
    // 4-6) fused conv + SiLU + mem + FIR + coupling -> eig, eig_bf
    cfc_kernel<<<dim3(Tn / TCH, Hn, Bn), dim3(256), 0, stream>>>(
        beta, mgp, conv_w, conv_b, log_decay, frequency, coupling, eig, eig_bf);
    // 7-8) fused: x1 = x + sigmoid(xn@gate_w^T + gate_b) * (eig@out_proj^T)
    gemm_bf<5, float><<<dim3(8, 128), dim3(256), 0, stream>>>(
        (const ushort*)xn_bf, (const ushort*)gate_bf, x1, NROW, Dn, Dn,
        gate_b, x, nullptr, (const ushort*)eig_bf, (const ushort*)outpj_bf, TWOK);
    // 9) y = LN2(x1) -> bf16
    ln_kernel<<<dim3(NROW), dim3(256), 0, stream>>>(x1, n2_g, n2_b, y_bf);
    // 10) MLP, 2 row-chunks of 8192
    for (int ck = 0; ck < 2; ++ck) {
        const size_t roff = (size_t)ck * 8192 * Dn;
        gemm_bf<3, __hip_bfloat16><<<dim3(32, 64), dim3(256), 0, stream>>>(
            (const ushort*)(y_bf + roff), (const ushort*)w1_bf, h1, 8192, Mmlp, Dn,
            mlp_b1, nullptr, nullptr, nullptr, nullptr, 0);
        gemm_bf<4, float><<<dim3(8, 64), dim3(256), 0, stream>>>(
            (const ushort*)h1, (const ushort*)w2_bf, out + roff, 8192, Dn, Mmlp,
            mlp_b2, x1 + roff, nullptr, nullptr, nullptr, 0);
    }
}